// Round 1
// baseline (362.750 us; speedup 1.0000x reference)
//
#include <hip/hip_runtime.h>
#include <hip/hip_bf16.h>
#include <stdint.h>

#define MM 4096
#define NN 4096
#define KK 4096
#define BM 128
#define BN 128
#define BK 32

typedef __bf16 bf16;
typedef __attribute__((ext_vector_type(8))) __bf16 bf16x8;
typedef __attribute__((ext_vector_type(4))) __bf16 bf16x4;
typedef __attribute__((ext_vector_type(4))) float f32x4;

__device__ inline const __attribute__((address_space(1))) void* to_global(const void* p) {
    return (const __attribute__((address_space(1))) void*)p;
}
__device__ inline __attribute__((address_space(3))) void* to_local(void* p) {
    return (__attribute__((address_space(3))) void*)p;
}

// x (M x K fp32, row-major) -> bf16 row-major
__global__ void convert_x(const float* __restrict__ x, bf16* __restrict__ out) {
    size_t i = ((size_t)blockIdx.x * blockDim.x + threadIdx.x) * 4;
    float4 v = *(const float4*)(x + i);
    bf16x4 o;
    o[0] = (bf16)v.x; o[1] = (bf16)v.y; o[2] = (bf16)v.z; o[3] = (bf16)v.w;
    *(bf16x4*)(out + i) = o;
}

// w, wnd: (K x N fp32, row-major). bt: (N x K bf16, row-major) = (w*wnd)^T
__global__ void convert_wt(const float* __restrict__ w, const float* __restrict__ wnd,
                           bf16* __restrict__ bt) {
    __shared__ float tile[32][33];
    int bx = blockIdx.x;   // n-tile
    int by = blockIdx.y;   // k-tile
    int tx = threadIdx.x;  // 0..31
    int ty = threadIdx.y;  // 0..7
    int n = bx * 32 + tx;
    #pragma unroll
    for (int r = ty; r < 32; r += 8) {
        size_t idx = (size_t)(by * 32 + r) * NN + n;
        tile[r][tx] = w[idx] * wnd[idx];
    }
    __syncthreads();
    int k2 = by * 32 + tx;
    #pragma unroll
    for (int r = ty; r < 32; r += 8) {
        int n2 = bx * 32 + r;
        bt[(size_t)n2 * KK + k2] = (bf16)tile[tx][r];
    }
}

// C = A * Bt^T + bias;  A: MxK bf16, Bt: NxK bf16, C: MxN fp32
__global__ __launch_bounds__(256, 3) void gemm_bt_bias(
    const bf16* __restrict__ A,
    const bf16* __restrict__ Bt,
    const float* __restrict__ bias,
    float* __restrict__ C) {
    __shared__ bf16 As[BM * BK];   // no padding: global_load_lds lane-order layout
    __shared__ bf16 Bs[BN * BK];

    const int t = threadIdx.x;
    const int wave = t >> 6;
    const int lane = t & 63;
    const int quad = lane >> 4;
    const int l15 = lane & 15;
    const int m0 = blockIdx.y * BM;
    const int n0 = blockIdx.x * BN;
    const int wm = wave >> 1;  // 0..1
    const int wn = wave & 1;   // 0..1

    f32x4 acc[4][4];
    #pragma unroll
    for (int i = 0; i < 4; ++i)
        #pragma unroll
        for (int j = 0; j < 4; ++j)
            acc[i][j] = (f32x4)0.0f;

    // staging: thread t, chunk c covers tile element (c*256+t)*8
    const int row_a0 = t >> 2;         // t/4
    const int col_a0 = (t & 3) * 8;
    const bf16* Ag = A + (size_t)(m0 + row_a0) * KK + col_a0;
    const bf16* Bg = Bt + (size_t)(n0 + row_a0) * KK + col_a0;

    for (int k0 = 0; k0 < KK; k0 += BK) {
        #pragma unroll
        for (int c = 0; c < 2; ++c) {
            __builtin_amdgcn_global_load_lds(
                to_global(Ag + k0 + (size_t)c * 64 * KK),
                to_local(As + ((size_t)c * 256 + wave * 64) * 8), 16, 0, 0);
            __builtin_amdgcn_global_load_lds(
                to_global(Bg + k0 + (size_t)c * 64 * KK),
                to_local(Bs + ((size_t)c * 256 + wave * 64) * 8), 16, 0, 0);
        }
        __syncthreads();

        bf16x8 af[4], bfr[4];
        #pragma unroll
        for (int i = 0; i < 4; ++i)
            af[i] = *(const bf16x8*)&As[(wm * 64 + i * 16 + l15) * BK + quad * 8];
        #pragma unroll
        for (int j = 0; j < 4; ++j)
            bfr[j] = *(const bf16x8*)&Bs[(wn * 64 + j * 16 + l15) * BK + quad * 8];

        #pragma unroll
        for (int i = 0; i < 4; ++i)
            #pragma unroll
            for (int j = 0; j < 4; ++j)
                acc[i][j] = __builtin_amdgcn_mfma_f32_16x16x32_bf16(af[i], bfr[j], acc[i][j], 0, 0, 0);

        __syncthreads();
    }

    // epilogue: C/D layout col=lane&15, row=quad*4+reg
    #pragma unroll
    for (int i = 0; i < 4; ++i) {
        #pragma unroll
        for (int j = 0; j < 4; ++j) {
            int col = n0 + wn * 64 + j * 16 + l15;
            float b = bias[col];
            #pragma unroll
            for (int r = 0; r < 4; ++r) {
                int row = m0 + wm * 64 + i * 16 + quad * 4 + r;
                C[(size_t)row * NN + col] = acc[i][j][r] + b;
            }
        }
    }
}

extern "C" void kernel_launch(void* const* d_in, const int* in_sizes, int n_in,
                              void* d_out, int out_size, void* d_ws, size_t ws_size,
                              hipStream_t stream) {
    const float* x = (const float*)d_in[0];
    const float* kern = (const float*)d_in[1];
    const float* wnd = (const float*)d_in[2];
    const float* bias = (const float*)d_in[3];
    float* out = (float*)d_out;

    bf16* Abf = (bf16*)d_ws;                                      // 32 MB
    bf16* Btbf = (bf16*)((char*)d_ws + (size_t)MM * KK * sizeof(bf16));  // +32 MB

    // 1) x -> bf16
    convert_x<<<(MM * (size_t)KK / 4 + 255) / 256, 256, 0, stream>>>(x, Abf);
    // 2) (kernel*window)^T -> bf16
    convert_wt<<<dim3(NN / 32, KK / 32), dim3(32, 8), 0, stream>>>(kern, wnd, Btbf);
    // 3) GEMM + bias
    gemm_bt_bias<<<dim3(NN / BN, MM / BM), 256, 0, stream>>>(Abf, Btbf, bias, out);
}

// Round 2
// 360.933 us; speedup vs baseline: 1.0050x; 1.0050x over previous
//
#include <hip/hip_runtime.h>
#include <hip/hip_bf16.h>
#include <stdint.h>

#define MM 4096
#define NN 4096
#define KK 4096
#define BM 128
#define BN 128
#define BK 32

typedef __bf16 bf16;
typedef __attribute__((ext_vector_type(8))) __bf16 bf16x8;
typedef __attribute__((ext_vector_type(4))) __bf16 bf16x4;
typedef __attribute__((ext_vector_type(4))) float f32x4;

__device__ inline const __attribute__((address_space(1))) void* to_global(const void* p) {
    return (const __attribute__((address_space(1))) void*)p;
}
__device__ inline __attribute__((address_space(3))) void* to_local(void* p) {
    return (__attribute__((address_space(3))) void*)p;
}

// x (M x K fp32, row-major) -> bf16 row-major. 8 elements/thread.
__global__ void convert_x(const float* __restrict__ x, bf16* __restrict__ out) {
    size_t i = ((size_t)blockIdx.x * blockDim.x + threadIdx.x) * 8;
    float4 v0 = *(const float4*)(x + i);
    float4 v1 = *(const float4*)(x + i + 4);
    bf16x8 o;
    o[0] = (bf16)v0.x; o[1] = (bf16)v0.y; o[2] = (bf16)v0.z; o[3] = (bf16)v0.w;
    o[4] = (bf16)v1.x; o[5] = (bf16)v1.y; o[6] = (bf16)v1.z; o[7] = (bf16)v1.w;
    *(bf16x8*)(out + i) = o;
}

// w, wnd: (K x N fp32, row-major). bt: (N x K bf16, row-major) = (w*wnd)^T
// 64k x 64n tile per 256-thread block. LDS transpose, wide loads+stores.
#define LDN 68  // bf16 elements per LDS row; 68*2=136 B = 8B-aligned rows, breaks conflicts
__global__ void convert_wt(const float* __restrict__ w, const float* __restrict__ wnd,
                           bf16* __restrict__ bt) {
    __shared__ bf16 Ts[64][LDN];  // [k][n]
    const int t = threadIdx.x;
    const int k0 = blockIdx.y * 64;
    const int n0 = blockIdx.x * 64;

    // Phase 1: coalesced float4 reads, fused mul, 8B LDS writes in [k][n]
    {
        const int nc = (t & 15) * 4;
        const int kb = t >> 4;  // 0..15
        #pragma unroll
        for (int p = 0; p < 4; ++p) {
            const int kl = p * 16 + kb;
            size_t idx = (size_t)(k0 + kl) * NN + (n0 + nc);
            float4 a = *(const float4*)(w + idx);
            float4 b = *(const float4*)(wnd + idx);
            bf16x4 o;
            o[0] = (bf16)(a.x * b.x);
            o[1] = (bf16)(a.y * b.y);
            o[2] = (bf16)(a.z * b.z);
            o[3] = (bf16)(a.w * b.w);
            *(bf16x4*)&Ts[kl][nc] = o;
        }
    }
    __syncthreads();

    // Phase 2: gather 8 k's per lane from LDS, 16B coalesced global stores
    {
        const int nl = t >> 2;  // 0..63
        #pragma unroll
        for (int p = 0; p < 2; ++p) {
            const int kc = (t & 3) + 4 * p;  // 0..7
            bf16x8 o;
            #pragma unroll
            for (int i = 0; i < 8; ++i) o[i] = Ts[kc * 8 + i][nl];
            *(bf16x8*)&bt[(size_t)(n0 + nl) * KK + k0 + kc * 8] = o;
        }
    }
}

// C = A * Bt^T + bias;  A: MxK bf16, Bt: NxK bf16, C: MxN fp32
__global__ __launch_bounds__(256, 3) void gemm_bt_bias(
    const bf16* __restrict__ A,
    const bf16* __restrict__ Bt,
    const float* __restrict__ bias,
    float* __restrict__ C) {
    __shared__ bf16 As[BM * BK];   // no padding: global_load_lds lane-order layout
    __shared__ bf16 Bs[BN * BK];

    const int t = threadIdx.x;
    const int wave = t >> 6;
    const int lane = t & 63;
    const int quad = lane >> 4;
    const int l15 = lane & 15;
    const int m0 = blockIdx.y * BM;
    const int n0 = blockIdx.x * BN;
    const int wm = wave >> 1;  // 0..1
    const int wn = wave & 1;   // 0..1

    f32x4 acc[4][4];
    #pragma unroll
    for (int i = 0; i < 4; ++i)
        #pragma unroll
        for (int j = 0; j < 4; ++j)
            acc[i][j] = (f32x4)0.0f;

    // staging: thread t, chunk c covers tile element (c*256+t)*8
    const int row_a0 = t >> 2;         // t/4
    const int col_a0 = (t & 3) * 8;
    const bf16* Ag = A + (size_t)(m0 + row_a0) * KK + col_a0;
    const bf16* Bg = Bt + (size_t)(n0 + row_a0) * KK + col_a0;

    for (int k0 = 0; k0 < KK; k0 += BK) {
        #pragma unroll
        for (int c = 0; c < 2; ++c) {
            __builtin_amdgcn_global_load_lds(
                to_global(Ag + k0 + (size_t)c * 64 * KK),
                to_local(As + ((size_t)c * 256 + wave * 64) * 8), 16, 0, 0);
            __builtin_amdgcn_global_load_lds(
                to_global(Bg + k0 + (size_t)c * 64 * KK),
                to_local(Bs + ((size_t)c * 256 + wave * 64) * 8), 16, 0, 0);
        }
        __syncthreads();

        bf16x8 af[4], bfr[4];
        #pragma unroll
        for (int i = 0; i < 4; ++i)
            af[i] = *(const bf16x8*)&As[(wm * 64 + i * 16 + l15) * BK + quad * 8];
        #pragma unroll
        for (int j = 0; j < 4; ++j)
            bfr[j] = *(const bf16x8*)&Bs[(wn * 64 + j * 16 + l15) * BK + quad * 8];

        #pragma unroll
        for (int i = 0; i < 4; ++i)
            #pragma unroll
            for (int j = 0; j < 4; ++j)
                acc[i][j] = __builtin_amdgcn_mfma_f32_16x16x32_bf16(af[i], bfr[j], acc[i][j], 0, 0, 0);

        __syncthreads();
    }

    // epilogue: C/D layout col=lane&15, row=quad*4+reg
    #pragma unroll
    for (int i = 0; i < 4; ++i) {
        #pragma unroll
        for (int j = 0; j < 4; ++j) {
            int col = n0 + wn * 64 + j * 16 + l15;
            float b = bias[col];
            #pragma unroll
            for (int r = 0; r < 4; ++r) {
                int row = m0 + wm * 64 + i * 16 + quad * 4 + r;
                C[(size_t)row * NN + col] = acc[i][j][r] + b;
            }
        }
    }
}

extern "C" void kernel_launch(void* const* d_in, const int* in_sizes, int n_in,
                              void* d_out, int out_size, void* d_ws, size_t ws_size,
                              hipStream_t stream) {
    const float* x = (const float*)d_in[0];
    const float* kern = (const float*)d_in[1];
    const float* wnd = (const float*)d_in[2];
    const float* bias = (const float*)d_in[3];
    float* out = (float*)d_out;

    bf16* Abf = (bf16*)d_ws;                                      // 32 MB
    bf16* Btbf = (bf16*)((char*)d_ws + (size_t)MM * KK * sizeof(bf16));  // +32 MB

    // 1) x -> bf16  (8 elems/thread)
    convert_x<<<(MM * (size_t)KK / 8 + 255) / 256, 256, 0, stream>>>(x, Abf);
    // 2) (kernel*window)^T -> bf16  (64x64 LDS-transpose tiles)
    convert_wt<<<dim3(NN / 64, KK / 64), 256, 0, stream>>>(kern, wnd, Btbf);
    // 3) GEMM + bias
    gemm_bt_bias<<<dim3(NN / BN, MM / BM), 256, 0, stream>>>(Abf, Btbf, bias, out);
}

// Round 3
// 356.856 us; speedup vs baseline: 1.0165x; 1.0114x over previous
//
#include <hip/hip_runtime.h>
#include <hip/hip_bf16.h>
#include <stdint.h>

#define MM 4096
#define NN 4096
#define KK 4096
#define BM 128
#define BN 128
#define BK 32

typedef __bf16 bf16;
typedef __attribute__((ext_vector_type(8))) __bf16 bf16x8;
typedef __attribute__((ext_vector_type(4))) __bf16 bf16x4;
typedef __attribute__((ext_vector_type(4))) float f32x4;

__device__ inline const __attribute__((address_space(1))) void* to_global(const void* p) {
    return (const __attribute__((address_space(1))) void*)p;
}
__device__ inline __attribute__((address_space(3))) void* to_local(void* p) {
    return (__attribute__((address_space(3))) void*)p;
}

// Fused prep: blocks [0,8192) convert x -> bf16 (8 elem/thread);
// blocks [8192,12288) convert (w*wnd)^T -> bf16 via 64x64 LDS-transpose tile.
#define LDN 68
#define NBX 8192  // MM*KK/8/256
__global__ void prep(const float* __restrict__ x,
                     const float* __restrict__ w,
                     const float* __restrict__ wnd,
                     bf16* __restrict__ Abf,
                     bf16* __restrict__ bt) {
    __shared__ bf16 Ts[64][LDN];
    const int t = threadIdx.x;
    int b = blockIdx.x;
    if (b < NBX) {
        size_t i = ((size_t)b * 256 + t) * 8;
        float4 v0 = *(const float4*)(x + i);
        float4 v1 = *(const float4*)(x + i + 4);
        bf16x8 o;
        o[0] = (bf16)v0.x; o[1] = (bf16)v0.y; o[2] = (bf16)v0.z; o[3] = (bf16)v0.w;
        o[4] = (bf16)v1.x; o[5] = (bf16)v1.y; o[6] = (bf16)v1.z; o[7] = (bf16)v1.w;
        *(bf16x8*)(Abf + i) = o;
        return;
    }
    b -= NBX;
    const int k0 = (b >> 6) * 64;
    const int n0 = (b & 63) * 64;

    // Phase 1: coalesced float4 reads, fused mul, 8B LDS writes in [k][n]
    {
        const int nc = (t & 15) * 4;
        const int kb = t >> 4;  // 0..15
        #pragma unroll
        for (int p = 0; p < 4; ++p) {
            const int kl = p * 16 + kb;
            size_t idx = (size_t)(k0 + kl) * NN + (n0 + nc);
            float4 a = *(const float4*)(w + idx);
            float4 m = *(const float4*)(wnd + idx);
            bf16x4 o;
            o[0] = (bf16)(a.x * m.x);
            o[1] = (bf16)(a.y * m.y);
            o[2] = (bf16)(a.z * m.z);
            o[3] = (bf16)(a.w * m.w);
            *(bf16x4*)&Ts[kl][nc] = o;
        }
    }
    __syncthreads();

    // Phase 2: gather 8 k's per lane from LDS, 16B coalesced global stores
    {
        const int nl = t >> 2;  // 0..63
        #pragma unroll
        for (int p = 0; p < 2; ++p) {
            const int kc = (t & 3) + 4 * p;  // 0..7
            bf16x8 o;
            #pragma unroll
            for (int i = 0; i < 8; ++i) o[i] = Ts[kc * 8 + i][nl];
            *(bf16x8*)&bt[(size_t)(n0 + nl) * KK + k0 + kc * 8] = o;
        }
    }
}

// C = A * Bt^T + bias;  A: MxK bf16, Bt: NxK bf16, C: MxN fp32
// XCD-aware swizzle: flat%8 = XCD (dispatch heuristic). XCD r owns n-tiles
// [4r,4r+4) x all 32 m-tiles -> B strip = 4*128*4096*2B = 4 MB = one L2.
__global__ __launch_bounds__(256, 4) void gemm_bt_bias(
    const bf16* __restrict__ A,
    const bf16* __restrict__ Bt,
    const float* __restrict__ bias,
    float* __restrict__ C) {
    __shared__ bf16 As[BM * BK];   // no padding: global_load_lds lane-order layout
    __shared__ bf16 Bs[BN * BK];

    const int t = threadIdx.x;
    const int wave = t >> 6;
    const int lane = t & 63;
    const int quad = lane >> 4;
    const int l15 = lane & 15;

    const int flat = blockIdx.y * 32 + blockIdx.x;
    const int xcd = flat & 7;
    const int idx = flat >> 3;               // 0..127
    const int n_tile = xcd * 4 + (idx & 3);  // bijective: (m,n) -> flat = (m*4+(n&3))*8 + n/4
    const int m_tile = idx >> 2;
    const int m0 = m_tile * BM;
    const int n0 = n_tile * BN;

    const int wm = wave >> 1;  // 0..1
    const int wn = wave & 1;   // 0..1

    f32x4 acc[4][4];
    #pragma unroll
    for (int i = 0; i < 4; ++i)
        #pragma unroll
        for (int j = 0; j < 4; ++j)
            acc[i][j] = (f32x4)0.0f;

    // staging: thread t, chunk c covers tile element (c*256+t)*8
    const int row_a0 = t >> 2;         // t/4
    const int col_a0 = (t & 3) * 8;
    const bf16* Ag = A + (size_t)(m0 + row_a0) * KK + col_a0;
    const bf16* Bg = Bt + (size_t)(n0 + row_a0) * KK + col_a0;

    for (int k0 = 0; k0 < KK; k0 += BK) {
        #pragma unroll
        for (int c = 0; c < 2; ++c) {
            __builtin_amdgcn_global_load_lds(
                to_global(Ag + k0 + (size_t)c * 64 * KK),
                to_local(As + ((size_t)c * 256 + wave * 64) * 8), 16, 0, 0);
            __builtin_amdgcn_global_load_lds(
                to_global(Bg + k0 + (size_t)c * 64 * KK),
                to_local(Bs + ((size_t)c * 256 + wave * 64) * 8), 16, 0, 0);
        }
        __syncthreads();

        bf16x8 af[4], bfr[4];
        #pragma unroll
        for (int i = 0; i < 4; ++i)
            af[i] = *(const bf16x8*)&As[(wm * 64 + i * 16 + l15) * BK + quad * 8];
        #pragma unroll
        for (int j = 0; j < 4; ++j)
            bfr[j] = *(const bf16x8*)&Bs[(wn * 64 + j * 16 + l15) * BK + quad * 8];

        #pragma unroll
        for (int i = 0; i < 4; ++i)
            #pragma unroll
            for (int j = 0; j < 4; ++j)
                acc[i][j] = __builtin_amdgcn_mfma_f32_16x16x32_bf16(af[i], bfr[j], acc[i][j], 0, 0, 0);

        __syncthreads();
    }

    // epilogue: C/D layout col=lane&15, row=quad*4+reg
    #pragma unroll
    for (int i = 0; i < 4; ++i) {
        #pragma unroll
        for (int j = 0; j < 4; ++j) {
            int col = n0 + wn * 64 + j * 16 + l15;
            float b = bias[col];
            #pragma unroll
            for (int r = 0; r < 4; ++r) {
                int row = m0 + wm * 64 + i * 16 + quad * 4 + r;
                C[(size_t)row * NN + col] = acc[i][j][r] + b;
            }
        }
    }
}

extern "C" void kernel_launch(void* const* d_in, const int* in_sizes, int n_in,
                              void* d_out, int out_size, void* d_ws, size_t ws_size,
                              hipStream_t stream) {
    const float* x = (const float*)d_in[0];
    const float* kern = (const float*)d_in[1];
    const float* wnd = (const float*)d_in[2];
    const float* bias = (const float*)d_in[3];
    float* out = (float*)d_out;

    bf16* Abf = (bf16*)d_ws;                                             // 32 MB
    bf16* Btbf = (bf16*)((char*)d_ws + (size_t)MM * KK * sizeof(bf16));  // +32 MB

    // 1) fused convert: x -> bf16, (kernel*window)^T -> bf16
    prep<<<NBX + (NN / 64) * (KK / 64), 256, 0, stream>>>(x, kern, wnd, Abf, Btbf);
    // 2) GEMM + bias
    gemm_bt_bias<<<dim3(32, 32), 256, 0, stream>>>(Abf, Btbf, bias, out);
}

// Round 4
// 330.855 us; speedup vs baseline: 1.0964x; 1.0786x over previous
//
#include <hip/hip_runtime.h>
#include <hip/hip_bf16.h>
#include <stdint.h>

#define MM 4096
#define NN 4096
#define KK 4096
#define BM 128
#define BN 128
#define BK 64

typedef __bf16 bf16;
typedef __attribute__((ext_vector_type(8))) __bf16 bf16x8;
typedef __attribute__((ext_vector_type(4))) __bf16 bf16x4;
typedef __attribute__((ext_vector_type(4))) float f32x4;

__device__ inline const __attribute__((address_space(1))) void* to_global(const void* p) {
    return (const __attribute__((address_space(1))) void*)p;
}
__device__ inline __attribute__((address_space(3))) void* to_local(void* p) {
    return (__attribute__((address_space(3))) void*)p;
}

// Fused prep: blocks [0,8192) convert x -> bf16 (8 elem/thread);
// blocks [8192,12288) convert (w*wnd)^T -> bf16 via 64x64 LDS-transpose tile.
#define LDN 68
#define NBX 8192  // MM*KK/8/256
__global__ void prep(const float* __restrict__ x,
                     const float* __restrict__ w,
                     const float* __restrict__ wnd,
                     bf16* __restrict__ Abf,
                     bf16* __restrict__ bt) {
    __shared__ bf16 Ts[64][LDN];
    const int t = threadIdx.x;
    int b = blockIdx.x;
    if (b < NBX) {
        size_t i = ((size_t)b * 256 + t) * 8;
        float4 v0 = *(const float4*)(x + i);
        float4 v1 = *(const float4*)(x + i + 4);
        bf16x8 o;
        o[0] = (bf16)v0.x; o[1] = (bf16)v0.y; o[2] = (bf16)v0.z; o[3] = (bf16)v0.w;
        o[4] = (bf16)v1.x; o[5] = (bf16)v1.y; o[6] = (bf16)v1.z; o[7] = (bf16)v1.w;
        *(bf16x8*)(Abf + i) = o;
        return;
    }
    b -= NBX;
    const int k0 = (b >> 6) * 64;
    const int n0 = (b & 63) * 64;

    // Phase 1: coalesced float4 reads, fused mul, 8B LDS writes in [k][n]
    {
        const int nc = (t & 15) * 4;
        const int kb = t >> 4;  // 0..15
        #pragma unroll
        for (int p = 0; p < 4; ++p) {
            const int kl = p * 16 + kb;
            size_t idx = (size_t)(k0 + kl) * NN + (n0 + nc);
            float4 a = *(const float4*)(w + idx);
            float4 m = *(const float4*)(wnd + idx);
            bf16x4 o;
            o[0] = (bf16)(a.x * m.x);
            o[1] = (bf16)(a.y * m.y);
            o[2] = (bf16)(a.z * m.z);
            o[3] = (bf16)(a.w * m.w);
            *(bf16x4*)&Ts[kl][nc] = o;
        }
    }
    __syncthreads();

    // Phase 2: gather 8 k's per lane from LDS, 16B coalesced global stores
    {
        const int nl = t >> 2;  // 0..63
        #pragma unroll
        for (int p = 0; p < 2; ++p) {
            const int kc = (t & 3) + 4 * p;  // 0..7
            bf16x8 o;
            #pragma unroll
            for (int i = 0; i < 8; ++i) o[i] = Ts[kc * 8 + i][nl];
            *(bf16x8*)&bt[(size_t)(n0 + nl) * KK + k0 + kc * 8] = o;
        }
    }
}

// C = A * Bt^T + bias;  A: MxK bf16, Bt: NxK bf16, C: MxN fp32
// BK=64: 64 K-iters (half the barrier drains of BK=32), 32 MFMA/wave/iter.
// LDS layout is XOR-swizzled to kill ds_read_b128 bank conflicts while
// respecting global_load_lds's wave-uniform-base + lane*16 constraint:
//   LDS slot (row r, 8-elem group g) holds global k-group g ^ (r&7).
__global__ __launch_bounds__(256, 4) void gemm_bt_bias(
    const bf16* __restrict__ A,
    const bf16* __restrict__ Bt,
    const float* __restrict__ bias,
    float* __restrict__ C) {
    __shared__ bf16 As[BM * BK];
    __shared__ bf16 Bs[BN * BK];

    const int t = threadIdx.x;
    const int wave = t >> 6;
    const int lane = t & 63;
    const int quad = lane >> 4;
    const int l15 = lane & 15;

    // XCD-aware swizzle: flat%8 = XCD; XCD r owns n-tiles [4r,4r+4) -> 4MB B strip = one L2
    const int flat = blockIdx.y * 32 + blockIdx.x;
    const int xcd = flat & 7;
    const int idx = flat >> 3;
    const int n_tile = xcd * 4 + (idx & 3);
    const int m_tile = idx >> 2;
    const int m0 = m_tile * BM;
    const int n0 = n_tile * BN;

    const int wm = wave >> 1;
    const int wn = wave & 1;

    f32x4 acc[4][4];
    #pragma unroll
    for (int i = 0; i < 4; ++i)
        #pragma unroll
        for (int j = 0; j < 4; ++j)
            acc[i][j] = (f32x4)0.0f;

    // Staging: thread t, chunk c covers LDS linear element (c*256+t)*8.
    // LDS (r, g): r = c*32 + (t>>3), g = t&7. Source global k-group = g ^ (r&7)
    // = (t&7) ^ ((t>>3)&7)  (c*32 = 0 mod 8 -> c-independent).
    const int row_s = t >> 3;                              // 0..31 (+32 per chunk)
    const int col_s = (((t & 7) ^ ((t >> 3) & 7))) * 8;    // swizzled k-offset
    const bf16* Ag = A + (size_t)(m0 + row_s) * KK + col_s;
    const bf16* Bg = Bt + (size_t)(n0 + row_s) * KK + col_s;

    for (int k0 = 0; k0 < KK; k0 += BK) {
        #pragma unroll
        for (int c = 0; c < 4; ++c) {
            __builtin_amdgcn_global_load_lds(
                to_global(Ag + k0 + (size_t)c * 32 * KK),
                to_local(As + ((size_t)c * 256 + wave * 64) * 8), 16, 0, 0);
            __builtin_amdgcn_global_load_lds(
                to_global(Bg + k0 + (size_t)c * 32 * KK),
                to_local(Bs + ((size_t)c * 256 + wave * 64) * 8), 16, 0, 0);
        }
        __syncthreads();

        #pragma unroll
        for (int s = 0; s < 2; ++s) {  // two k=32 steps within BK=64
            bf16x8 af[4], bfr[4];
            #pragma unroll
            for (int i = 0; i < 4; ++i) {
                const int R = wm * 64 + i * 16 + l15;
                const int g = (s * 4 + quad) ^ (l15 & 7);  // swizzled group
                af[i] = *(const bf16x8*)&As[R * BK + g * 8];
            }
            #pragma unroll
            for (int j = 0; j < 4; ++j) {
                const int R = wn * 64 + j * 16 + l15;
                const int g = (s * 4 + quad) ^ (l15 & 7);
                bfr[j] = *(const bf16x8*)&Bs[R * BK + g * 8];
            }
            #pragma unroll
            for (int i = 0; i < 4; ++i)
                #pragma unroll
                for (int j = 0; j < 4; ++j)
                    acc[i][j] = __builtin_amdgcn_mfma_f32_16x16x32_bf16(af[i], bfr[j], acc[i][j], 0, 0, 0);
        }

        __syncthreads();
    }

    // epilogue: C/D layout col=lane&15, row=quad*4+reg
    #pragma unroll
    for (int i = 0; i < 4; ++i) {
        #pragma unroll
        for (int j = 0; j < 4; ++j) {
            int col = n0 + wn * 64 + j * 16 + l15;
            float b = bias[col];
            #pragma unroll
            for (int r = 0; r < 4; ++r) {
                int row = m0 + wm * 64 + i * 16 + quad * 4 + r;
                C[(size_t)row * NN + col] = acc[i][j][r] + b;
            }
        }
    }
}

extern "C" void kernel_launch(void* const* d_in, const int* in_sizes, int n_in,
                              void* d_out, int out_size, void* d_ws, size_t ws_size,
                              hipStream_t stream) {
    const float* x = (const float*)d_in[0];
    const float* kern = (const float*)d_in[1];
    const float* wnd = (const float*)d_in[2];
    const float* bias = (const float*)d_in[3];
    float* out = (float*)d_out;

    bf16* Abf = (bf16*)d_ws;                                             // 32 MB
    bf16* Btbf = (bf16*)((char*)d_ws + (size_t)MM * KK * sizeof(bf16));  // +32 MB

    // 1) fused convert: x -> bf16, (kernel*window)^T -> bf16
    prep<<<NBX + (NN / 64) * (KK / 64), 256, 0, stream>>>(x, kern, wnd, Abf, Btbf);
    // 2) GEMM + bias
    gemm_bt_bias<<<dim3(32, 32), 256, 0, stream>>>(Abf, Btbf, bias, out);
}